// Round 7
// baseline (3241.666 us; speedup 1.0000x reference)
//
#include <hip/hip_runtime.h>

#define HID     1024
#define TSTEPS  19
#define INDIM   17
#define XSTRIDE (TSTEPS * INDIM)

typedef unsigned short u16;
typedef unsigned int   u32;
typedef __attribute__((ext_vector_type(8))) _Float16 f16x8;  // 8 fp16 = 4 VGPRs
typedef __attribute__((ext_vector_type(4))) float f32x4;

__device__ __forceinline__ u16 f2h(float f) {  // fp32 -> fp16 RNE
    union { _Float16 h; u16 u; } v; v.h = (_Float16)f; return v.u;
}
__device__ __forceinline__ float h2f(u16 x) {
    union { _Float16 h; u16 u; } v; v.u = x; return (float)v.h;
}
__device__ __forceinline__ float sigm(float x) {
    x = fminf(fmaxf(x, -30.f), 30.f);
    return 1.f / (1.f + __expf(-x));
}
__device__ __forceinline__ float tanhr(float x) {
    x = fminf(fmaxf(x, -15.f), 15.f);
    float e = __expf(-2.f * x);
    return (1.f - e) / (1.f + e);
}

// Async global->LDS, 16B per lane: HW writes wave-uniform LDS base + lane*16.
__device__ __forceinline__ void gload_lds16(const u16* g, u16* l) {
    __builtin_amdgcn_global_load_lds(
        (const __attribute__((address_space(1))) u32*)g,
        (__attribute__((address_space(3))) u32*)l, 16, 0, 0);
}

// fp32 -> fp16 hi (+ optional fp16 lo residual) split.
__global__ __launch_bounds__(256) void split_kernel(
    const float* __restrict__ src, u16* __restrict__ hi, u16* __restrict__ lo, int n4)
{
    int i = blockIdx.x * blockDim.x + threadIdx.x;
    if (i >= n4) return;
    float4 v = ((const float4*)src)[i];
    ushort4 h, l;
    h.x = f2h(v.x); l.x = f2h(v.x - h2f(h.x));
    h.y = f2h(v.y); l.y = f2h(v.y - h2f(h.y));
    h.z = f2h(v.z); l.z = f2h(v.z - h2f(h.z));
    h.w = f2h(v.w); l.w = f2h(v.w - h2f(h.w));
    ((ushort4*)hi)[i] = h;
    if (lo) ((ushort4*)lo)[i] = l;
}

// Fused GEMM + LSTM cell body (r5-proven structure, single-term fp16 GEMMs).
// gates(128x128 tile of B x 4H) = sum over (a0,w0),(a1,w1) fp16 pairs of
// A@W^T (+ packed 3-term x-part) + (bi + bh); then per-lane LSTM cell.
// Tile: vcol = gate*32 + du so all 4 gates of (b,u) land in the same lane.
// LDS [row][64k] with XOR chunk swizzle (2-way alias only -> free).
// Staging via global_load_lds dwordx4 (wave-uniform LDS base + lane*16B).
__device__ __forceinline__ void gate_body(
    u16* lA, u16* lB, int bid,
    const u16* __restrict__ a0, const u16* __restrict__ w0,
    const u16* __restrict__ a1, const u16* __restrict__ w1,
    const float* __restrict__ bi, const float* __restrict__ bh,
    const u16* __restrict__ xAhi, const u16* __restrict__ xAlo,
    const u16* __restrict__ xWhi, const u16* __restrict__ xWlo, int t,
    float* __restrict__ cbuf, u16* __restrict__ outh,
    int first, int nsrc)
{
    const int tid  = threadIdx.x;
    const int wave = tid >> 6;
    const int lane = tid & 63;
    const int col  = lane & 15;   // MFMA A/B m|n index; C/D col
    const int quad = lane >> 4;   // MFMA k-group; C/D row group
    const int rb   = (bid & 31) * 128;   // batch row block
    const int u0   = (bid >> 5) * 32;    // hidden-unit block

    const int lr = lane >> 3;         // staging row-in-group-of-8
    const int ck = (lane & 7) ^ lr;   // xor-swizzled global chunk to fetch

    f32x4 acc[4][8];
    const f32x4 fzero = {0.f, 0.f, 0.f, 0.f};
#pragma unroll
    for (int i = 0; i < 4; ++i)
#pragma unroll
        for (int j = 0; j < 8; ++j) acc[i][j] = fzero;

    const int nst = nsrc << 4;  // 16 stages of BK=64 per (A,W) pair
    for (int s = 0; s < nst; ++s) {
        const u16* Asrc = (s < 16) ? a0 : a1;
        const u16* Wsrc = (s < 16) ? w0 : w1;
        const int k0 = (s & 15) * 64;

        __syncthreads();  // previous stage's LDS reads done
#pragma unroll
        for (int i = 0; i < 8; ++i) {   // A: rows of this wave's 64-row slab
            const int rbase = wave * 64 + i * 8;
            const int r = rbase + lr;
            const u16* gp = Asrc + (size_t)(rb + r) * HID + k0 + ck * 8;
            gload_lds16(gp, lA + rbase * 64);   // lane lands at +lane*16B
        }
#pragma unroll
        for (int i = 0; i < 8; ++i) {   // B: weight rows via vcol->n mapping
            const int vbase = wave * 64 + i * 8;
            const int v = vbase + lr;
            const int n = ((v >> 5) << 10) + u0 + (v & 31);  // gate*1024 + u
            const u16* gp = Wsrc + (size_t)n * HID + k0 + ck * 8;
            gload_lds16(gp, lB + vbase * 64);
        }
        __syncthreads();  // staging visible (barrier drains vmcnt)

#pragma unroll
        for (int ks = 0; ks < 2; ++ks) {
            const int p = ((ks << 2) + quad) ^ (col & 7);  // swizzled chunk
            f16x8 av[4], bv[8];
#pragma unroll
            for (int rf = 0; rf < 4; ++rf)
                av[rf] = *(const f16x8*)(lA + (wave * 64 + rf * 16 + col) * 64 + p * 8);
#pragma unroll
            for (int cf = 0; cf < 8; ++cf)
                bv[cf] = *(const f16x8*)(lB + (cf * 16 + col) * 64 + p * 8);
#pragma unroll
            for (int rf = 0; rf < 4; ++rf)
#pragma unroll
                for (int cf = 0; cf < 8; ++cf)
                    acc[rf][cf] = __builtin_amdgcn_mfma_f32_16x16x32_f16(
                        av[rf], bv[cf], acc[rf][cf], 0, 0, 0);
        }
    }

    if (xAhi) {  // layer 1 x-part: 3-term fp16 split packed into one K=64
                 // block: A = [xhi | xlo | xhi | 0], W = [Whi | Whi | Wlo | 0]
        __syncthreads();
        {
            const int r = tid;  // 128 threads stage 128 rows each
            const int rx = r & 7;
            const size_t xoff = (size_t)(rb + r) * XSTRIDE + (size_t)t * INDIM;
            const u16* ah = xAhi + xoff;
            const u16* al = xAlo + xoff;
            const int n = ((r >> 5) << 10) + u0 + (r & 31);
            const u16* wh = xWhi + (size_t)n * INDIM;
            const u16* wl = xWlo + (size_t)n * INDIM;
#pragma unroll
            for (int k = 0; k < 64; ++k) {
                u16 av_ = 0, wv_ = 0;
                if (k < INDIM)          { av_ = ah[k];             wv_ = wh[k]; }
                else if (k < 2 * INDIM) { av_ = al[k - INDIM];     wv_ = wh[k - INDIM]; }
                else if (k < 3 * INDIM) { av_ = ah[k - 2 * INDIM]; wv_ = wl[k - 2 * INDIM]; }
                const int pos = (((k >> 3) ^ rx) << 3) + (k & 7);
                lA[r * 64 + pos] = av_;
                lB[r * 64 + pos] = wv_;
            }
        }
        __syncthreads();
#pragma unroll
        for (int ks = 0; ks < 2; ++ks) {
            const int p = ((ks << 2) + quad) ^ (col & 7);
            f16x8 av[4], bv[8];
#pragma unroll
            for (int rf = 0; rf < 4; ++rf)
                av[rf] = *(const f16x8*)(lA + (wave * 64 + rf * 16 + col) * 64 + p * 8);
#pragma unroll
            for (int cf = 0; cf < 8; ++cf)
                bv[cf] = *(const f16x8*)(lB + (cf * 16 + col) * 64 + p * 8);
#pragma unroll
            for (int rf = 0; rf < 4; ++rf)
#pragma unroll
                for (int cf = 0; cf < 8; ++cf)
                    acc[rf][cf] = __builtin_amdgcn_mfma_f32_16x16x32_f16(
                        av[rf], bv[cf], acc[rf][cf], 0, 0, 0);
        }
    }

    // Epilogue: per-lane LSTM cell. C/D layout: col=lane&15, row=quad*4+reg.
    // Gates of unit u = u0 + s2*16 + col live at cf = {s2, 2+s2, 4+s2, 6+s2}.
#pragma unroll
    for (int s2 = 0; s2 < 2; ++s2) {
        const int u = u0 + s2 * 16 + col;
        const float bI = bi[u]           + bh[u];
        const float bF = bi[HID + u]     + bh[HID + u];
        const float bG = bi[2 * HID + u] + bh[2 * HID + u];
        const float bO = bi[3 * HID + u] + bh[3 * HID + u];
#pragma unroll
        for (int rf = 0; rf < 4; ++rf) {
#pragma unroll
            for (int rr = 0; rr < 4; ++rr) {
                const int brow = rb + wave * 64 + rf * 16 + quad * 4 + rr;
                const size_t idx = (size_t)brow * HID + u;
                const float iv = sigm(acc[rf][0 + s2][rr] + bI);
                const float fv = sigm(acc[rf][2 + s2][rr] + bF);
                const float gv = tanhr(acc[rf][4 + s2][rr] + bG);
                const float ov = sigm(acc[rf][6 + s2][rr] + bO);
                const float cold = first ? 0.f : cbuf[idx];
                const float cn = fv * cold + iv * gv;
                const float hn = ov * tanhr(cn);
                cbuf[idx] = cn;
                outh[idx] = f2h(hn);
            }
        }
    }
}

// out[b, t, :] = h2[b,:] @ W_lin^T + b_lin in fp32 (h2 fp16).
// 128 threads = 2 waves x 4 rows = 8 batch rows per block (512 blocks).
__device__ __forceinline__ void out_body(int oid,
    const u16* __restrict__ h2h,
    const float* __restrict__ Wlin, const float* __restrict__ blin,
    float* __restrict__ out, int t)
{
    const int tid = threadIdx.x;
    const int wave = tid >> 6, lane = tid & 63;
    const int rw = lane >> 4, q = lane & 15;
    const int b = oid * 8 + wave * 4 + rw;
    const u16* hh = h2h + (size_t)b * HID;
    float acc[INDIM];
#pragma unroll
    for (int j = 0; j < INDIM; ++j) acc[j] = 0.f;
#pragma unroll 4
    for (int it = 0; it < 16; ++it) {
        const int u = q * 64 + it * 4;
        const ushort4 a = *(const ushort4*)(hh + u);
        const float h0 = h2f(a.x), h1 = h2f(a.y), h2 = h2f(a.z), h3 = h2f(a.w);
#pragma unroll
        for (int j = 0; j < INDIM; ++j) {
            const float4 w = *(const float4*)(Wlin + j * HID + u);
            acc[j] += h0 * w.x + h1 * w.y + h2 * w.z + h3 * w.w;
        }
    }
#pragma unroll
    for (int j = 0; j < INDIM; ++j) {   // reduce across the 16 q-slices
        float v = acc[j];
        v += __shfl_xor(v, 1);
        v += __shfl_xor(v, 2);
        v += __shfl_xor(v, 4);
        v += __shfl_xor(v, 8);
        acc[j] = v;
    }
    const size_t ob = (size_t)b * XSTRIDE + (size_t)t * INDIM;
    float mine = acc[0];
#pragma unroll
    for (int j = 1; j < 16; ++j) if (q == j) mine = acc[j];
    out[ob + q] = mine + blin[q];
    if (q == 0) out[ob + 16] = acc[16] + blin[16];
}

// Fused pipeline step C(s) = { L2(s-1) | L1(s) | OUT(s-2) }, partitioned by
// block id. Roles are mutually independent; h1/h2 rotate through FOUR slabs
// (h1[t&3] written by L1(t), h2[t&3] by L2(t)) so every intra-launch buffer
// set is disjoint, every RAW spans >=1 launch and every WAR spans >=3
// launches (r6's 2-deep ping-pong had zero WAR slack and failed at 1.8e-2).
__global__ __launch_bounds__(128, 2) void step_kernel(
    int nA, int nB,
    // role A: layer 2 of step s-1
    const u16* __restrict__ Aa0, const u16* __restrict__ Aw0,
    const u16* __restrict__ Aa1, const u16* __restrict__ Aw1,
    const float* __restrict__ Abi, const float* __restrict__ Abh,
    float* __restrict__ Acbuf, u16* __restrict__ Aouth, int Afirst, int Ansrc,
    // role B: layer 1 of step s
    const u16* __restrict__ Ba0, const u16* __restrict__ Bw0,
    const float* __restrict__ Bbi, const float* __restrict__ Bbh,
    const u16* __restrict__ xAhi, const u16* __restrict__ xAlo,
    const u16* __restrict__ xWhi, const u16* __restrict__ xWlo, int Bt,
    float* __restrict__ Bcbuf, u16* __restrict__ Bouth, int Bfirst, int Bnsrc,
    // role O: output linear of step s-2
    const u16* __restrict__ Oh2, const float* __restrict__ Wlin,
    const float* __restrict__ blin, float* __restrict__ outp, int Ot)
{
    __shared__ u16 lA[128 * 64];
    __shared__ u16 lB[128 * 64];
    const int bid = blockIdx.x;
    if (bid < nA) {
        gate_body(lA, lB, bid, Aa0, Aw0, Aa1, Aw1, Abi, Abh,
                  nullptr, nullptr, nullptr, nullptr, 0,
                  Acbuf, Aouth, Afirst, Ansrc);
    } else if (bid < nA + nB) {
        gate_body(lA, lB, bid - nA, Ba0, Bw0, nullptr, nullptr, Bbi, Bbh,
                  xAhi, xAlo, xWhi, xWlo, Bt,
                  Bcbuf, Bouth, Bfirst, Bnsrc);
    } else {
        out_body(bid - nA - nB, Oh2, Wlin, blin, outp, Ot);
    }
}

extern "C" void kernel_launch(void* const* d_in, const int* in_sizes, int n_in,
                              void* d_out, int out_size, void* d_ws, size_t ws_size,
                              hipStream_t stream)
{
    const float* x     = (const float*)d_in[0];
    const float* W_ih1 = (const float*)d_in[1];
    const float* W_hh1 = (const float*)d_in[2];
    const float* b_ih1 = (const float*)d_in[3];
    const float* b_hh1 = (const float*)d_in[4];
    const float* W_ih2 = (const float*)d_in[5];
    const float* W_hh2 = (const float*)d_in[6];
    const float* b_ih2 = (const float*)d_in[7];
    const float* b_hh2 = (const float*)d_in[8];
    const float* W_lin = (const float*)d_in[9];
    const float* b_lin = (const float*)d_in[10];
    float* out = (float*)d_out;
    char* ws = (char*)d_ws;
    const size_t MB = (size_t)1 << 20;

    // Workspace layout (~130 MB; no memset -- first=1 skips all reads of
    // uninitialized state at t=0). h1/h2: FOUR 8MB fp16 slabs each, indexed
    // by t&3 (the slab L1(t)/L2(t) writes).
    float* c1 = (float*)(ws);             // 16 MB (4096x1024 fp32)
    float* c2 = (float*)(ws + 16 * MB);   // 16 MB
    u16* h1[4] = { (u16*)(ws + 32 * MB), (u16*)(ws + 40 * MB),
                   (u16*)(ws + 48 * MB), (u16*)(ws + 56 * MB) };
    u16* h2[4] = { (u16*)(ws + 64 * MB), (u16*)(ws + 72 * MB),
                   (u16*)(ws + 80 * MB), (u16*)(ws + 88 * MB) };
    u16* w1h  = (u16*)(ws + 96 * MB);     // 8 MB each (4H x H fp16)
    u16* w2ih = (u16*)(ws + 104 * MB);
    u16* w2hh = (u16*)(ws + 112 * MB);
    u16* xh   = (u16*)(ws + 120 * MB);    // 4 MB slots (x: 2.6 MB fp16)
    u16* xl   = (u16*)(ws + 124 * MB);
    u16* wxh  = (u16*)(ws + 128 * MB);    // 1 MB slots (W_ih1: 136 KB fp16)
    u16* wxl  = (u16*)(ws + 129 * MB);

    // One-time fp32 -> fp16 splits (weights: hi only; x and W_ih1: hi+lo).
    const int nW  = 4 * HID * HID / 4;       // 1048576 float4s
    const int nX  = 4096 * XSTRIDE / 4;      // 330752
    const int nWx = 4 * HID * INDIM / 4;     // 17408
    split_kernel<<<(nW  + 255) / 256, 256, 0, stream>>>(W_hh1, w1h,  nullptr, nW);
    split_kernel<<<(nW  + 255) / 256, 256, 0, stream>>>(W_ih2, w2ih, nullptr, nW);
    split_kernel<<<(nW  + 255) / 256, 256, 0, stream>>>(W_hh2, w2hh, nullptr, nW);
    split_kernel<<<(nX  + 255) / 256, 256, 0, stream>>>(x,     xh,   xl,      nX);
    split_kernel<<<(nWx + 255) / 256, 256, 0, stream>>>(W_ih1, wxh,  wxl,     nWx);

    // Software pipeline: C(s) = { L2(s-1), L1(s), OUT(s-2) }, s = 0..TSTEPS+1.
    // Slabs: L1(t): reads h1[(t+3)&3], writes h1[t&3];
    //        L2(t): reads h1[t&3], h2[(t+3)&3], writes h2[t&3];
    //        OUT(t): reads h2[t&3].
    // Intra-launch C(s): writes {h1[s&3], h2[(s-1)&3]}, reads {h1[(s-1)&3],
    // h1[(s+3)&3], h2[(s+2)&3]} -- disjoint; WAR distance = 3 launches.
    for (int s = 0; s <= TSTEPS + 1; ++s) {
        const int ta = s - 1, tb = s, to = s - 2;
        const int nA = (s >= 1 && s <= TSTEPS) ? 1024 : 0;
        const int nB = (s <= TSTEPS - 1) ? 1024 : 0;
        const int nO = (s >= 2) ? 512 : 0;
        step_kernel<<<nA + nB + nO, 128, 0, stream>>>(
            nA, nB,
            // A: L2(ta) = h1[ta&3]@w2ih + h2[(ta+3)&3]@w2hh -> h2[ta&3]
            h1[ta & 3], w2ih, h2[(ta + 3) & 3], w2hh, b_ih2, b_hh2,
            c2, h2[ta & 3], (ta == 0) ? 1 : 0, (ta == 0) ? 1 : 2,
            // B: L1(tb) = x_tb@W_ih1 + h1[(tb+3)&3]@w1h -> h1[tb&3]
            h1[(tb + 3) & 3], w1h, b_ih1, b_hh1, xh, xl, wxh, wxl, tb,
            c1, h1[tb & 3], (tb == 0) ? 1 : 0, (tb == 0) ? 0 : 1,
            // O: OUT(to) reads h2[to&3]
            h2[to & 3], W_lin, b_lin, out, to);
    }
    (void)in_sizes; (void)n_in; (void)out_size; (void)ws_size;
}

// Round 8
// 3108.369 us; speedup vs baseline: 1.0429x; 1.0429x over previous
//
#include <hip/hip_runtime.h>

#define HID     1024
#define TSTEPS  19
#define INDIM   17
#define XSTRIDE (TSTEPS * INDIM)

typedef unsigned short u16;
typedef unsigned int   u32;
typedef __attribute__((ext_vector_type(8))) _Float16 f16x8;  // 8 fp16 = 4 VGPRs
typedef __attribute__((ext_vector_type(4))) float f32x4;

__device__ __forceinline__ u16 f2h(float f) {  // fp32 -> fp16 RNE
    union { _Float16 h; u16 u; } v; v.h = (_Float16)f; return v.u;
}
__device__ __forceinline__ float h2f(u16 x) {
    union { _Float16 h; u16 u; } v; v.u = x; return (float)v.h;
}
__device__ __forceinline__ float sigm(float x) {
    x = fminf(fmaxf(x, -30.f), 30.f);
    return 1.f / (1.f + __expf(-x));
}
__device__ __forceinline__ float tanhr(float x) {
    x = fminf(fmaxf(x, -15.f), 15.f);
    float e = __expf(-2.f * x);
    return (1.f - e) / (1.f + e);
}

// Async global->LDS, 16B per lane: HW writes wave-uniform LDS base + lane*16.
__device__ __forceinline__ void gload_lds16(const u16* g, u16* l) {
    __builtin_amdgcn_global_load_lds(
        (const __attribute__((address_space(1))) u32*)g,
        (__attribute__((address_space(3))) u32*)l, 16, 0, 0);
}

// fp32 -> fp16 hi (+ optional fp16 lo residual) split.
__global__ __launch_bounds__(256) void split_kernel(
    const float* __restrict__ src, u16* __restrict__ hi, u16* __restrict__ lo, int n4)
{
    int i = blockIdx.x * blockDim.x + threadIdx.x;
    if (i >= n4) return;
    float4 v = ((const float4*)src)[i];
    ushort4 h, l;
    h.x = f2h(v.x); l.x = f2h(v.x - h2f(h.x));
    h.y = f2h(v.y); l.y = f2h(v.y - h2f(h.y));
    h.z = f2h(v.z); l.z = f2h(v.z - h2f(h.z));
    h.w = f2h(v.w); l.w = f2h(v.w - h2f(h.w));
    ((ushort4*)hi)[i] = h;
    if (lo) ((ushort4*)lo)[i] = l;
}

// Fused GEMM + LSTM cell body (r5-proven structure, single-term fp16 GEMMs).
// gates(128x128 tile of B x 4H) = sum over (a0,w0),(a1,w1) fp16 pairs of
// A@W^T (+ packed 3-term x-part) + (bi + bh); then per-lane LSTM cell.
// Tile: vcol = gate*32 + du so all 4 gates of (b,u) land in the same lane.
// LDS [row][64k] with XOR chunk swizzle (2-way alias only -> free).
// Staging via global_load_lds dwordx4 (wave-uniform LDS base + lane*16B).
__device__ __forceinline__ void gate_body(
    u16* lA, u16* lB, int bid,
    const u16* __restrict__ a0, const u16* __restrict__ w0,
    const u16* __restrict__ a1, const u16* __restrict__ w1,
    const float* __restrict__ bi, const float* __restrict__ bh,
    const u16* __restrict__ xAhi, const u16* __restrict__ xAlo,
    const u16* __restrict__ xWhi, const u16* __restrict__ xWlo, int t,
    float* __restrict__ cbuf, u16* __restrict__ outh,
    int first, int nsrc)
{
    const int tid  = threadIdx.x;
    const int wave = tid >> 6;
    const int lane = tid & 63;
    const int col  = lane & 15;   // MFMA A/B m|n index; C/D col
    const int quad = lane >> 4;   // MFMA k-group; C/D row group
    const int rb   = (bid & 31) * 128;   // batch row block
    const int u0   = (bid >> 5) * 32;    // hidden-unit block

    const int lr = lane >> 3;         // staging row-in-group-of-8
    const int ck = (lane & 7) ^ lr;   // xor-swizzled global chunk to fetch

    f32x4 acc[4][8];
    const f32x4 fzero = {0.f, 0.f, 0.f, 0.f};
#pragma unroll
    for (int i = 0; i < 4; ++i)
#pragma unroll
        for (int j = 0; j < 8; ++j) acc[i][j] = fzero;

    const int nst = nsrc << 4;  // 16 stages of BK=64 per (A,W) pair
    for (int s = 0; s < nst; ++s) {
        const u16* Asrc = (s < 16) ? a0 : a1;
        const u16* Wsrc = (s < 16) ? w0 : w1;
        const int k0 = (s & 15) * 64;

        __syncthreads();  // previous stage's (or previous body's) reads done
#pragma unroll
        for (int i = 0; i < 8; ++i) {   // A: rows of this wave's 64-row slab
            const int rbase = wave * 64 + i * 8;
            const int r = rbase + lr;
            const u16* gp = Asrc + (size_t)(rb + r) * HID + k0 + ck * 8;
            gload_lds16(gp, lA + rbase * 64);   // lane lands at +lane*16B
        }
#pragma unroll
        for (int i = 0; i < 8; ++i) {   // B: weight rows via vcol->n mapping
            const int vbase = wave * 64 + i * 8;
            const int v = vbase + lr;
            const int n = ((v >> 5) << 10) + u0 + (v & 31);  // gate*1024 + u
            const u16* gp = Wsrc + (size_t)n * HID + k0 + ck * 8;
            gload_lds16(gp, lB + vbase * 64);
        }
        __syncthreads();  // staging visible (barrier drains vmcnt)

#pragma unroll
        for (int ks = 0; ks < 2; ++ks) {
            const int p = ((ks << 2) + quad) ^ (col & 7);  // swizzled chunk
            f16x8 av[4], bv[8];
#pragma unroll
            for (int rf = 0; rf < 4; ++rf)
                av[rf] = *(const f16x8*)(lA + (wave * 64 + rf * 16 + col) * 64 + p * 8);
#pragma unroll
            for (int cf = 0; cf < 8; ++cf)
                bv[cf] = *(const f16x8*)(lB + (cf * 16 + col) * 64 + p * 8);
#pragma unroll
            for (int rf = 0; rf < 4; ++rf)
#pragma unroll
                for (int cf = 0; cf < 8; ++cf)
                    acc[rf][cf] = __builtin_amdgcn_mfma_f32_16x16x32_f16(
                        av[rf], bv[cf], acc[rf][cf], 0, 0, 0);
        }
    }

    if (xAhi) {  // layer 1 x-part: 3-term fp16 split packed into one K=64
                 // block: A = [xhi | xlo | xhi | 0], W = [Whi | Whi | Wlo | 0]
        __syncthreads();
        {
            const int r = tid;  // 128 threads stage 128 rows each
            const int rx = r & 7;
            const size_t xoff = (size_t)(rb + r) * XSTRIDE + (size_t)t * INDIM;
            const u16* ah = xAhi + xoff;
            const u16* al = xAlo + xoff;
            const int n = ((r >> 5) << 10) + u0 + (r & 31);
            const u16* wh = xWhi + (size_t)n * INDIM;
            const u16* wl = xWlo + (size_t)n * INDIM;
#pragma unroll
            for (int k = 0; k < 64; ++k) {
                u16 av_ = 0, wv_ = 0;
                if (k < INDIM)          { av_ = ah[k];             wv_ = wh[k]; }
                else if (k < 2 * INDIM) { av_ = al[k - INDIM];     wv_ = wh[k - INDIM]; }
                else if (k < 3 * INDIM) { av_ = ah[k - 2 * INDIM]; wv_ = wl[k - 2 * INDIM]; }
                const int pos = (((k >> 3) ^ rx) << 3) + (k & 7);
                lA[r * 64 + pos] = av_;
                lB[r * 64 + pos] = wv_;
            }
        }
        __syncthreads();
#pragma unroll
        for (int ks = 0; ks < 2; ++ks) {
            const int p = ((ks << 2) + quad) ^ (col & 7);
            f16x8 av[4], bv[8];
#pragma unroll
            for (int rf = 0; rf < 4; ++rf)
                av[rf] = *(const f16x8*)(lA + (wave * 64 + rf * 16 + col) * 64 + p * 8);
#pragma unroll
            for (int cf = 0; cf < 8; ++cf)
                bv[cf] = *(const f16x8*)(lB + (cf * 16 + col) * 64 + p * 8);
#pragma unroll
            for (int rf = 0; rf < 4; ++rf)
#pragma unroll
                for (int cf = 0; cf < 8; ++cf)
                    acc[rf][cf] = __builtin_amdgcn_mfma_f32_16x16x32_f16(
                        av[rf], bv[cf], acc[rf][cf], 0, 0, 0);
        }
    }

    // Epilogue: per-lane LSTM cell. C/D layout: col=lane&15, row=quad*4+reg.
    // Gates of unit u = u0 + s2*16 + col live at cf = {s2, 2+s2, 4+s2, 6+s2}.
#pragma unroll
    for (int s2 = 0; s2 < 2; ++s2) {
        const int u = u0 + s2 * 16 + col;
        const float bI = bi[u]           + bh[u];
        const float bF = bi[HID + u]     + bh[HID + u];
        const float bG = bi[2 * HID + u] + bh[2 * HID + u];
        const float bO = bi[3 * HID + u] + bh[3 * HID + u];
#pragma unroll
        for (int rf = 0; rf < 4; ++rf) {
#pragma unroll
            for (int rr = 0; rr < 4; ++rr) {
                const int brow = rb + wave * 64 + rf * 16 + quad * 4 + rr;
                const size_t idx = (size_t)brow * HID + u;
                const float iv = sigm(acc[rf][0 + s2][rr] + bI);
                const float fv = sigm(acc[rf][2 + s2][rr] + bF);
                const float gv = tanhr(acc[rf][4 + s2][rr] + bG);
                const float ov = sigm(acc[rf][6 + s2][rr] + bO);
                const float cold = first ? 0.f : cbuf[idx];
                const float cn = fv * cold + iv * gv;
                const float hn = ov * tanhr(cn);
                cbuf[idx] = cn;
                outh[idx] = f2h(hn);
            }
        }
    }
}

// out[b, t, :] = h2[b,:] @ W_lin^T + b_lin in fp32 (h2 fp16).
// 128 threads = 2 waves x 4 rows = 8 batch rows per block (512 blocks).
__device__ __forceinline__ void out_body(int oid,
    const u16* __restrict__ h2h,
    const float* __restrict__ Wlin, const float* __restrict__ blin,
    float* __restrict__ out, int t)
{
    const int tid = threadIdx.x;
    const int wave = tid >> 6, lane = tid & 63;
    const int rw = lane >> 4, q = lane & 15;
    const int b = oid * 8 + wave * 4 + rw;
    const u16* hh = h2h + (size_t)b * HID;
    float acc[INDIM];
#pragma unroll
    for (int j = 0; j < INDIM; ++j) acc[j] = 0.f;
#pragma unroll 4
    for (int it = 0; it < 16; ++it) {
        const int u = q * 64 + it * 4;
        const ushort4 a = *(const ushort4*)(hh + u);
        const float h0 = h2f(a.x), h1 = h2f(a.y), h2 = h2f(a.z), h3 = h2f(a.w);
#pragma unroll
        for (int j = 0; j < INDIM; ++j) {
            const float4 w = *(const float4*)(Wlin + j * HID + u);
            acc[j] += h0 * w.x + h1 * w.y + h2 * w.z + h3 * w.w;
        }
    }
#pragma unroll
    for (int j = 0; j < INDIM; ++j) {   // reduce across the 16 q-slices
        float v = acc[j];
        v += __shfl_xor(v, 1);
        v += __shfl_xor(v, 2);
        v += __shfl_xor(v, 4);
        v += __shfl_xor(v, 8);
        acc[j] = v;
    }
    const size_t ob = (size_t)b * XSTRIDE + (size_t)t * INDIM;
    float mine = acc[0];
#pragma unroll
    for (int j = 1; j < 16; ++j) if (q == j) mine = acc[j];
    out[ob + q] = mine + blin[q];
    if (q == 0) out[ob + 16] = acc[16] + blin[16];
}

// Fused pipeline step C(s) = { L2(s-1) + L1(s) | OUT(s-2) }. HOMOGENEOUS gate
// blocks: each of the 1024 gate blocks (bid < nG) runs BOTH role A (layer 2,
// step s-1) and role B (layer 1, step s) for its (rb,u0) tile -- uniform work
// per block, no heterogeneous-tail imbalance (r7: mixed 2:1.3:0.03 block
// lengths cost ~35%). The 512 tiny O blocks go LAST in bid order to backfill
// the gate drain tail. Buffer schedule identical to r7's verified 4-deep
// rotation: intra-launch sets disjoint, RAW >= 1 launch, WAR >= 3 launches.
__global__ __launch_bounds__(128, 2) void step_kernel(
    int nG, int doA, int doB,
    // role A: layer 2 of step s-1
    const u16* __restrict__ Aa0, const u16* __restrict__ Aw0,
    const u16* __restrict__ Aa1, const u16* __restrict__ Aw1,
    const float* __restrict__ Abi, const float* __restrict__ Abh,
    float* __restrict__ Acbuf, u16* __restrict__ Aouth, int Afirst, int Ansrc,
    // role B: layer 1 of step s
    const u16* __restrict__ Ba0, const u16* __restrict__ Bw0,
    const float* __restrict__ Bbi, const float* __restrict__ Bbh,
    const u16* __restrict__ xAhi, const u16* __restrict__ xAlo,
    const u16* __restrict__ xWhi, const u16* __restrict__ xWlo, int Bt,
    float* __restrict__ Bcbuf, u16* __restrict__ Bouth, int Bfirst, int Bnsrc,
    // role O: output linear of step s-2
    const u16* __restrict__ Oh2, const float* __restrict__ Wlin,
    const float* __restrict__ blin, float* __restrict__ outp, int Ot)
{
    __shared__ u16 lA[128 * 64];
    __shared__ u16 lB[128 * 64];
    const int bid = blockIdx.x;
    if (bid < nG) {
        if (doA)
            gate_body(lA, lB, bid, Aa0, Aw0, Aa1, Aw1, Abi, Abh,
                      nullptr, nullptr, nullptr, nullptr, 0,
                      Acbuf, Aouth, Afirst, Ansrc);
        if (doB)
            gate_body(lA, lB, bid, Ba0, Bw0, nullptr, nullptr, Bbi, Bbh,
                      xAhi, xAlo, xWhi, xWlo, Bt,
                      Bcbuf, Bouth, Bfirst, Bnsrc);
    } else {
        out_body(bid - nG, Oh2, Wlin, blin, outp, Ot);
    }
}

extern "C" void kernel_launch(void* const* d_in, const int* in_sizes, int n_in,
                              void* d_out, int out_size, void* d_ws, size_t ws_size,
                              hipStream_t stream)
{
    const float* x     = (const float*)d_in[0];
    const float* W_ih1 = (const float*)d_in[1];
    const float* W_hh1 = (const float*)d_in[2];
    const float* b_ih1 = (const float*)d_in[3];
    const float* b_hh1 = (const float*)d_in[4];
    const float* W_ih2 = (const float*)d_in[5];
    const float* W_hh2 = (const float*)d_in[6];
    const float* b_ih2 = (const float*)d_in[7];
    const float* b_hh2 = (const float*)d_in[8];
    const float* W_lin = (const float*)d_in[9];
    const float* b_lin = (const float*)d_in[10];
    float* out = (float*)d_out;
    char* ws = (char*)d_ws;
    const size_t MB = (size_t)1 << 20;

    // Workspace layout (~130 MB; no memset -- first=1 skips all reads of
    // uninitialized state at t=0). h1/h2: FOUR 8MB fp16 slabs each, indexed
    // by t&3 (the slab L1(t)/L2(t) writes).
    float* c1 = (float*)(ws);             // 16 MB (4096x1024 fp32)
    float* c2 = (float*)(ws + 16 * MB);   // 16 MB
    u16* h1[4] = { (u16*)(ws + 32 * MB), (u16*)(ws + 40 * MB),
                   (u16*)(ws + 48 * MB), (u16*)(ws + 56 * MB) };
    u16* h2[4] = { (u16*)(ws + 64 * MB), (u16*)(ws + 72 * MB),
                   (u16*)(ws + 80 * MB), (u16*)(ws + 88 * MB) };
    u16* w1h  = (u16*)(ws + 96 * MB);     // 8 MB each (4H x H fp16)
    u16* w2ih = (u16*)(ws + 104 * MB);
    u16* w2hh = (u16*)(ws + 112 * MB);
    u16* xh   = (u16*)(ws + 120 * MB);    // 4 MB slots (x: 2.6 MB fp16)
    u16* xl   = (u16*)(ws + 124 * MB);
    u16* wxh  = (u16*)(ws + 128 * MB);    // 1 MB slots (W_ih1: 136 KB fp16)
    u16* wxl  = (u16*)(ws + 129 * MB);

    // One-time fp32 -> fp16 splits (weights: hi only; x and W_ih1: hi+lo).
    const int nW  = 4 * HID * HID / 4;       // 1048576 float4s
    const int nX  = 4096 * XSTRIDE / 4;      // 330752
    const int nWx = 4 * HID * INDIM / 4;     // 17408
    split_kernel<<<(nW  + 255) / 256, 256, 0, stream>>>(W_hh1, w1h,  nullptr, nW);
    split_kernel<<<(nW  + 255) / 256, 256, 0, stream>>>(W_ih2, w2ih, nullptr, nW);
    split_kernel<<<(nW  + 255) / 256, 256, 0, stream>>>(W_hh2, w2hh, nullptr, nW);
    split_kernel<<<(nX  + 255) / 256, 256, 0, stream>>>(x,     xh,   xl,      nX);
    split_kernel<<<(nWx + 255) / 256, 256, 0, stream>>>(W_ih1, wxh,  wxl,     nWx);

    // Software pipeline: C(s) = { L2(s-1) + L1(s), OUT(s-2) }, s = 0..TSTEPS+1.
    // Slabs: L1(t): reads h1[(t+3)&3], writes h1[t&3];
    //        L2(t): reads h1[t&3], h2[(t+3)&3], writes h2[t&3];
    //        OUT(t): reads h2[t&3].
    // Intra-launch C(s): writes {h1[s&3], h2[(s-1)&3]}, reads {h1[(s-1)&3],
    // h1[(s+3)&3], h2[(s+2)&3]} -- disjoint; WAR distance = 3 launches.
    for (int s = 0; s <= TSTEPS + 1; ++s) {
        const int ta = s - 1, tb = s, to = s - 2;
        const int doA = (s >= 1 && s <= TSTEPS) ? 1 : 0;
        const int doB = (s <= TSTEPS - 1) ? 1 : 0;
        const int nG = (doA || doB) ? 1024 : 0;
        const int nO = (s >= 2) ? 512 : 0;
        step_kernel<<<nG + nO, 128, 0, stream>>>(
            nG, doA, doB,
            // A: L2(ta) = h1[ta&3]@w2ih + h2[(ta+3)&3]@w2hh -> h2[ta&3]
            h1[ta & 3], w2ih, h2[(ta + 3) & 3], w2hh, b_ih2, b_hh2,
            c2, h2[ta & 3], (ta == 0) ? 1 : 0, (ta == 0) ? 1 : 2,
            // B: L1(tb) = x_tb@W_ih1 + h1[(tb+3)&3]@w1h -> h1[tb&3]
            h1[(tb + 3) & 3], w1h, b_ih1, b_hh1, xh, xl, wxh, wxl, tb,
            c1, h1[tb & 3], (tb == 0) ? 1 : 0, (tb == 0) ? 0 : 1,
            // O: OUT(to) reads h2[to&3]
            h2[to & 3], W_lin, b_lin, out, to);
    }
    (void)in_sizes; (void)n_in; (void)out_size; (void)ws_size;
}